// Round 6
// baseline (670.053 us; speedup 1.0000x reference)
//
#include <hip/hip_runtime.h>
#include <hip/hip_bf16.h>

// GPT block: x -> QKV -> causal MHA -> O-proj(+x) -> LN1 -> FFN(GELU) -> (+x1) -> LN2
// B=4 S=2048 D=1024 H=16 hd=64 DFF=4096. All matmuls bf16 MFMA (fp32 accum).
// Workspace layout (bytes):
//   0      wb_qkv  [3072,1024] bf16    6 MB
//   6M     wb_o    [1024,1024] bf16    2 MB
//   8M     wb_1    [4096,1024] bf16    8 MB
//   16M    wb_2    [1024,4096] bf16    8 MB
//   24M    xb      [8192,1024] bf16 (x; later x1 bf16)          16 MB
//   40M    attb    [8192,1024] bf16 (attention out, token-major) 16 MB
//   56M    x1f     [8192,1024] f32 (y1 pre-LN, then x1 post-LN)  32 MB
//   88M    qb/hb   qb [64bh,2048,64] bf16 16MB; hb [8192,4096] bf16 64MB (reuse)
//   104M   kb      [64bh,2048,64] bf16 16 MB
//   120M   vbt     [64bh,64,2048] bf16 (V TRANSPOSED per head) 16 MB
// total 152 MB. FFN2 writes f32 straight to d_out; LN2 runs in place there.

typedef unsigned short u16;
typedef unsigned int u32;
typedef short s16x8 __attribute__((ext_vector_type(8)));   // bf16 MFMA frag
typedef float f32x4 __attribute__((ext_vector_type(4)));
typedef float f32x16 __attribute__((ext_vector_type(16)));
typedef unsigned short u16x8 __attribute__((ext_vector_type(8)));
typedef unsigned short u16x4 __attribute__((ext_vector_type(4)));
typedef unsigned int u32x4 __attribute__((ext_vector_type(4)));

#define MFMA16(a, b, c) __builtin_amdgcn_mfma_f32_16x16x32_bf16(a, b, c, 0, 0, 0)
#define MFMA32(a, b, c) __builtin_amdgcn_mfma_f32_32x32x16_bf16(a, b, c, 0, 0, 0)

#define GLDS16(g, l)                                                     \
  __builtin_amdgcn_global_load_lds(                                     \
      (const __attribute__((address_space(1))) unsigned int*)(g),       \
      (__attribute__((address_space(3))) unsigned int*)(l), 16, 0, 0)

__device__ __forceinline__ u16 f2bf(float f) {
  unsigned u = __builtin_bit_cast(unsigned, f);
  u += 0x7fffu + ((u >> 16) & 1u);   // RNE (inputs are never NaN here)
  return (u16)(u >> 16);
}

// XOR swizzle for 128B-row LDS tiles: permutes 16B chunks within a row by row&7.
__device__ __forceinline__ int swz(int b) { return b ^ (((b >> 7) & 7) << 4); }

// ---------------------------------------------------------------- conversions
struct CvtArgs {
  const float* src[7];
  u16* dst[7];
  int start[8];   // cumulative region starts, in blocks
};

__global__ __launch_bounds__(256) void cvt_all(CvtArgs a) {
  int b = blockIdx.x;
  int r = 0;
#pragma unroll
  for (int i = 1; i < 7; i++) r += (b >= a.start[i]);
  long i = (long)(b - a.start[r]) * 256 + threadIdx.x;
  const float4* s = (const float4*)a.src[r];
  float4 va = s[2 * i], vb = s[2 * i + 1];
  u16x8 o;
  o[0] = f2bf(va.x); o[1] = f2bf(va.y); o[2] = f2bf(va.z); o[3] = f2bf(va.w);
  o[4] = f2bf(vb.x); o[5] = f2bf(vb.y); o[6] = f2bf(vb.z); o[7] = f2bf(vb.w);
  ((u16x8*)a.dst[r])[i] = o;
}

// ---------------------------------------------------------------- GEMM v2 (NT)
// C[m,n] = sum_k A[m,k] * Bt[n,k]; 128x128 tile, BK=64, 8 waves (32x64 each),
// double-buffered LDS (64 KB -> 2 blocks/CU), 2-phase loop: STAGE(t+1) issued
// before compute(t), ONE barrier per K-step (T3 minimal recipe). 1D grid with
// bijective XCD swizzle (grid % 8 == 0 for all our shapes).
// EPI: 0=QKV split(+bias, Q*=0.125 -> qb/kb [bh,s,hd]; V -> vbt [bh,hd,s] T)
//      1=Oproj (+bias +x residual -> f32)
//      2=FFN1  (+bias, exact GELU -> bf16, ld 4096)
//      3=FFN2  (+bias +x1 residual -> f32)
template <int EPI>
__global__ __launch_bounds__(512, 4) void gemm2(
    const u16* __restrict__ A, const u16* __restrict__ Bt, int K, int NB,
    const float* __restrict__ c0, const float* __restrict__ c1,
    const float* __restrict__ c2, const float* __restrict__ resid,
    u16* __restrict__ ob0, u16* __restrict__ ob1, u16* __restrict__ ob2,
    float* __restrict__ of) {
  __shared__ u16 As[2][128 * 64];
  __shared__ u16 Bs[2][128 * 64];
  const int tid = threadIdx.x, w = tid >> 6, l = tid & 63;
  const int wrow = w >> 1, wcol = w & 1;          // 4M x 2N wave grid
  const int nwg = gridDim.x, cpx = nwg >> 3, lid = blockIdx.x;
  const int sid = (lid & 7) * cpx + (lid >> 3);   // XCD-contiguous chunks
  const long row0 = (long)(sid / NB) * 128, col0 = (long)(sid % NB) * 128;

  f32x4 acc[2][4];
#pragma unroll
  for (int i = 0; i < 2; i++)
#pragma unroll
    for (int j = 0; j < 4; j++) acc[i][j] = f32x4{0.f, 0.f, 0.f, 0.f};

  // staging: wave w, instr i covers tile rows [i*64 + w*8, +8); lane l ->
  // row +(l>>3), 16B k-chunk (l&7). LDS linear [128 rows][64 k] per buffer.
  const u16* Ag = A + (row0 + w * 8 + (l >> 3)) * (long)K + (l & 7) * 8;
  const u16* Bg = Bt + (col0 + w * 8 + (l >> 3)) * (long)K + (l & 7) * 8;

#define STAGE2(bf, k0)                                                \
  GLDS16(Ag + (k0),                &As[bf][(w * 8) * 64]);            \
  GLDS16(Ag + (k0) + 64 * (long)K, &As[bf][(64 + w * 8) * 64]);       \
  GLDS16(Bg + (k0),                &Bs[bf][(w * 8) * 64]);            \
  GLDS16(Bg + (k0) + 64 * (long)K, &Bs[bf][(64 + w * 8) * 64]);

  const int nt = K >> 6;
  int cur = 0;
  STAGE2(0, 0)
  __syncthreads();                    // vmcnt(0) drain included
  for (int t = 0; t < nt; ++t) {
    if (t + 1 < nt) { STAGE2(cur ^ 1, (t + 1) << 6) }  // in flight across compute
#pragma unroll
    for (int ks = 0; ks < 2; ks++) {
      s16x8 af[2], bfr[4];
#pragma unroll
      for (int mi = 0; mi < 2; mi++)
        af[mi] = *(const s16x8*)(&As[cur][(wrow * 32 + mi * 16 + (l & 15)) * 64 +
                                          ks * 32 + (l >> 4) * 8]);
#pragma unroll
      for (int ni = 0; ni < 4; ni++)
        bfr[ni] = *(const s16x8*)(&Bs[cur][(wcol * 64 + ni * 16 + (l & 15)) * 64 +
                                           ks * 32 + (l >> 4) * 8]);
#pragma unroll
      for (int mi = 0; mi < 2; mi++)
#pragma unroll
        for (int ni = 0; ni < 4; ni++)
          acc[mi][ni] = MFMA16(af[mi], bfr[ni], acc[mi][ni]);
    }
    __syncthreads();                  // STAGE done + all reads of cur done
    cur ^= 1;
  }
#undef STAGE2

#pragma unroll
  for (int mi = 0; mi < 2; mi++)
#pragma unroll
    for (int ni = 0; ni < 4; ni++) {
      long rbase = row0 + wrow * 32 + mi * 16 + ((l >> 4) << 2);
      long col = col0 + wcol * 64 + ni * 16 + (l & 15);
#pragma unroll
      for (int r = 0; r < 4; r++) {
        long row = rbase + r;
        float v = acc[mi][ni][r];
        if constexpr (EPI == 0) {
          int which = (int)(col >> 10);
          int ec = (int)(col & 1023);
          const float* bias = which == 0 ? c0 : (which == 1 ? c1 : c2);
          v += bias[ec];
          if (which == 0) v *= 0.125f;      // 1/sqrt(hd)
          int hh = ec >> 6, dd = ec & 63;
          long bb = row >> 11, sl = row & 2047;
          if (which == 2) {
            ob2[(((bb * 16 + hh) * 64 + dd) << 11) + sl] = f2bf(v);  // V^T
          } else {
            u16* dst = which == 0 ? ob0 : ob1;
            dst[(((bb * 16 + hh) * 2048 + sl) << 6) + dd] = f2bf(v);
          }
        } else if constexpr (EPI == 1) {
          v += c0[col] + resid[row * 1024 + col];
          of[row * 1024 + col] = v;
        } else if constexpr (EPI == 2) {
          v += c0[col];
          v = 0.5f * v * (1.f + erff(v * 0.70710678118654752f));
          ob0[row * 4096 + col] = f2bf(v);
        } else {
          v += c0[col] + resid[row * 1024 + col];
          of[row * 1024 + col] = v;
        }
      }
    }
}

// ---------------------------------------------------------------- attention v2
// Per block: one (b,h), QBLK=128 (4 waves x 32 q-rows). KVBLK=64.
// Swapped QK^T via 32x32x16 MFMA: P[q][s] with q=lane&31 (lane-local row).
// Softmax fully in-register (in-lane reduce + one shfl_xor(32)).
// P -> B-frag repack in-register (pack + shfl_xor(32) + select).
// PV computed as O^T = mfma(V^T, P): per-lane scalar rescale.
// K and V^T staged by global_load_lds with pre-swizzled global source,
// double-buffered, one barrier per tile.
__global__ __launch_bounds__(256, 4) void attn2_kernel(const u16* __restrict__ Qb,
                                                       const u16* __restrict__ Kb,
                                                       const u16* __restrict__ Vbt,
                                                       u16* __restrict__ attb) {
  __shared__ u16 Kt[2][64 * 64];     // [buf][s=64 rows][64 d] swizzled chunks
  __shared__ u16 Vt[2][64 * 64];     // [buf][d=64 rows][64 s] swizzled chunks

  const int tid = threadIdx.x, w = tid >> 6, l = tid & 63;
  const int hi = l >> 5, ln = l & 31;
  const int bh = blockIdx.y;
  const int qt = (int)gridDim.x - 1 - (int)blockIdx.x;  // heavy tiles first
  const int q0w = qt * 128 + w * 32;                    // wave's first q row
  const int q = q0w + ln;                               // this lane's q row
  const long kbase = (long)bh * (2048 * 64);
  const long vbase = (long)bh * (64 * 2048);
  const int tmax = 2 * qt + 1;
  const int cs = (l & 7) ^ ((l >> 3) & 7);              // pre-swizzled source chunk

  // hoist Q row into registers: qf[kk] = Q[q][kk*16 + hi*8 .. +8)
  s16x8 qf[4];
  {
    const char* qp = (const char*)(Qb + kbase) + (long)q * 128 + hi * 16;
#pragma unroll
    for (int kk = 0; kk < 4; kk++) qf[kk] = *(const s16x8*)(qp + kk * 32);
  }

  f32x16 acc0, acc1;
#pragma unroll
  for (int i = 0; i < 16; i++) { acc0[i] = 0.f; acc1[i] = 0.f; }
  float mrow = -1e30f, lsum = 0.f;

  // stage(buf, t): wave w stages K rows [w*16, w*16+16) and V^T rows likewise.
  const u16* kg = Kb + kbase;
  const u16* vg = Vbt + vbase;
#define STAGE(bf, t)                                                            \
  {                                                                             \
    int s0_ = (t) * 64;                                                         \
    GLDS16(kg + (long)(s0_ + w * 16 + (l >> 3)) * 64 + cs * 8,                  \
           (char*)Kt[bf] + w * 2048);                                           \
    GLDS16(kg + (long)(s0_ + w * 16 + 8 + (l >> 3)) * 64 + cs * 8,              \
           (char*)Kt[bf] + w * 2048 + 1024);                                    \
    GLDS16(vg + (long)(w * 16 + (l >> 3)) * 2048 + s0_ + cs * 8,                \
           (char*)Vt[bf] + w * 2048);                                           \
    GLDS16(vg + (long)(w * 16 + 8 + (l >> 3)) * 2048 + s0_ + cs * 8,            \
           (char*)Vt[bf] + w * 2048 + 1024);                                    \
  }

  STAGE(0, 0);

  for (int t = 0; t <= tmax; ++t) {
    __syncthreads();                 // drains this wave's global_load_lds too
    const int cur = t & 1;
    if (t < tmax) STAGE(cur ^ 1, t + 1);
    if (64 * t > q0w + 31) continue; // wave fully masked for this tile (still staged)
    const int s0 = t * 64;

    // ---- QK^T (swapped): p{sb}[r] = P[q][s0 + 32*sb + crow(r,hi)]
    f32x16 p0, p1;
#pragma unroll
    for (int i = 0; i < 16; i++) { p0[i] = 0.f; p1[i] = 0.f; }
#pragma unroll
    for (int kk = 0; kk < 4; kk++) {
      s16x8 kf0 = *(const s16x8*)((char*)Kt[cur] + swz(ln * 128 + kk * 32 + hi * 16));
      s16x8 kf1 = *(const s16x8*)((char*)Kt[cur] + swz((32 + ln) * 128 + kk * 32 + hi * 16));
      p0 = MFMA32(kf0, qf[kk], p0);
      p1 = MFMA32(kf1, qf[kk], p1);
    }

    // ---- causal mask (only near the diagonal)
    if (s0 + 63 > q0w) {
#pragma unroll
      for (int r = 0; r < 16; r++) {
        int so = (r & 3) + 8 * (r >> 2) + 4 * hi;
        if (s0 + so > q) p0[r] = -1e30f;
        if (s0 + 32 + so > q) p1[r] = -1e30f;
      }
    }

    // ---- online softmax (row q is lane-local across the two hi halves)
    float mt = -1e30f;
#pragma unroll
    for (int r = 0; r < 16; r++) { mt = fmaxf(mt, p0[r]); mt = fmaxf(mt, p1[r]); }
    mt = fmaxf(mt, __shfl_xor(mt, 32, 64));
    float mnew = fmaxf(mrow, mt);
    float corr = __expf(mrow - mnew);
    float lp = 0.f;
#pragma unroll
    for (int r = 0; r < 16; r++) {
      p0[r] = __expf(p0[r] - mnew); lp += p0[r];
      p1[r] = __expf(p1[r] - mnew); lp += p1[r];
    }
    lp += __shfl_xor(lp, 32, 64);
    lsum = lsum * corr + lp;
    mrow = mnew;
#pragma unroll
    for (int i = 0; i < 16; i++) { acc0[i] *= corr; acc1[i] *= corr; }

    // ---- repack P into B-fragments pa[kb]: element j = P[q][16*kb + 8*hi + j]
    u32x4 pa[4];
#pragma unroll
    for (int kb = 0; kb < 4; kb++) {
      const int b8 = 8 * (kb & 1);
#pragma unroll
      for (int tt = 0; tt < 2; tt++) {
        float a0, a1, b0, b1;
        if (kb < 2) {
          a0 = p0[b8 + 2 * tt]; a1 = p0[b8 + 2 * tt + 1];
          b0 = p0[b8 + 4 + 2 * tt]; b1 = p0[b8 + 5 + 2 * tt];
        } else {
          a0 = p1[b8 + 2 * tt]; a1 = p1[b8 + 2 * tt + 1];
          b0 = p1[b8 + 4 + 2 * tt]; b1 = p1[b8 + 5 + 2 * tt];
        }
        u32 X = (u32)f2bf(a0) | ((u32)f2bf(a1) << 16);
        u32 Y = (u32)f2bf(b0) | ((u32)f2bf(b1) << 16);
        u32 Xx = __shfl_xor(X, 32, 64), Yx = __shfl_xor(Y, 32, 64);
        pa[kb][tt]     = (hi == 0) ? X : Yx;   // words 0,1 (k bit2 = 0 half)
        pa[kb][tt + 2] = (hi == 0) ? Xx : Y;   // words 2,3
      }
    }

    // ---- PV as O^T: acc[dblk] += mfma(A=V^T frag, B=pa)
#pragma unroll
    for (int kb = 0; kb < 4; kb++) {
      s16x8 pf = __builtin_bit_cast(s16x8, pa[kb]);
      s16x8 vf0 = *(const s16x8*)((char*)Vt[cur] + swz(ln * 128 + kb * 32 + hi * 16));
      s16x8 vf1 = *(const s16x8*)((char*)Vt[cur] + swz((32 + ln) * 128 + kb * 32 + hi * 16));
      acc0 = MFMA32(vf0, pf, acc0);
      acc1 = MFMA32(vf1, pf, acc1);
    }
  }

  // ---- epilogue: attb[b*2048+q][h*64+d], d = 32*dblk + crow(reg,hi)
  const float inv = 1.0f / lsum;
  const long orow = ((long)(bh >> 4) * 2048 + q) * 1024 + (bh & 15) * 64;
#pragma unroll
  for (int dblk = 0; dblk < 2; dblk++) {
#pragma unroll
    for (int rq = 0; rq < 4; rq++) {
      u16x4 o;
#pragma unroll
      for (int e = 0; e < 4; e++) {
        float v = (dblk == 0 ? acc0[rq * 4 + e] : acc1[rq * 4 + e]) * inv;
        o[e] = f2bf(v);
      }
      int d = 32 * dblk + 8 * rq + 4 * hi;
      *(u16x4*)(attb + orow + d) = o;
    }
  }
#undef STAGE
}

// ---------------------------------------------------------------- layernorm
__global__ __launch_bounds__(256) void ln_kernel(const float* __restrict__ in,
                                                 float* __restrict__ outf,
                                                 u16* __restrict__ outb,
                                                 const float* __restrict__ g,
                                                 const float* __restrict__ be) {
  __shared__ float a1[4], a2[4];
  long row = blockIdx.x;
  const float4* p = (const float4*)(in + row * 1024);
  int t = threadIdx.x, w = t >> 6, l = t & 63;
  float4 v = p[t];
  float s = v.x + v.y + v.z + v.w;
#pragma unroll
  for (int off = 1; off < 64; off <<= 1) s += __shfl_xor(s, off, 64);
  if (l == 0) a1[w] = s;
  __syncthreads();
  float mu = (a1[0] + a1[1] + a1[2] + a1[3]) * (1.f / 1024.f);
  float d0 = v.x - mu, d1 = v.y - mu, d2 = v.z - mu, d3 = v.w - mu;
  float q = d0 * d0 + d1 * d1 + d2 * d2 + d3 * d3;
#pragma unroll
  for (int off = 1; off < 64; off <<= 1) q += __shfl_xor(q, off, 64);
  if (l == 0) a2[w] = q;
  __syncthreads();
  float var = (a2[0] + a2[1] + a2[2] + a2[3]) * (1.f / 1024.f);
  float rs = rsqrtf(var + 1e-5f);
  float4 gg = ((const float4*)g)[t], bb = ((const float4*)be)[t];
  float o0 = d0 * rs * gg.x + bb.x, o1 = d1 * rs * gg.y + bb.y;
  float o2 = d2 * rs * gg.z + bb.z, o3 = d3 * rs * gg.w + bb.w;
  if (outf) {
    float4 o; o.x = o0; o.y = o1; o.z = o2; o.w = o3;
    ((float4*)(outf + row * 1024))[t] = o;
  }
  if (outb) {
    u16x4 u; u[0] = f2bf(o0); u[1] = f2bf(o1); u[2] = f2bf(o2); u[3] = f2bf(o3);
    ((u16x4*)outb)[row * 256 + t] = u;
  }
}

// ---------------------------------------------------------------- launch
extern "C" void kernel_launch(void* const* d_in, const int* in_sizes, int n_in,
                              void* d_out, int out_size, void* d_ws, size_t ws_size,
                              hipStream_t stream) {
  const float* x   = (const float*)d_in[0];
  const float* Wq  = (const float*)d_in[1];
  const float* bq  = (const float*)d_in[2];
  const float* Wk  = (const float*)d_in[3];
  const float* bk  = (const float*)d_in[4];
  const float* Wv  = (const float*)d_in[5];
  const float* bv  = (const float*)d_in[6];
  const float* Wo  = (const float*)d_in[7];
  const float* bo  = (const float*)d_in[8];
  const float* W1  = (const float*)d_in[9];
  const float* b1  = (const float*)d_in[10];
  const float* W2  = (const float*)d_in[11];
  const float* b2  = (const float*)d_in[12];
  const float* g1  = (const float*)d_in[13];
  const float* be1 = (const float*)d_in[14];
  const float* g2  = (const float*)d_in[15];
  const float* be2 = (const float*)d_in[16];

  char* ws = (char*)d_ws;
  const size_t MB = 1ull << 20;
  u16*   wb_qkv = (u16*)(ws + 0);
  u16*   wb_o   = (u16*)(ws + 6 * MB);
  u16*   wb_1   = (u16*)(ws + 8 * MB);
  u16*   wb_2   = (u16*)(ws + 16 * MB);
  u16*   xb     = (u16*)(ws + 24 * MB);   // x bf16, later x1 bf16
  u16*   attb   = (u16*)(ws + 40 * MB);
  float* x1f    = (float*)(ws + 56 * MB);
  u16*   qb     = (u16*)(ws + 88 * MB);
  u16*   kb     = (u16*)(ws + 104 * MB);
  u16*   vbt    = (u16*)(ws + 120 * MB);  // V transposed [bh][64][2048]
  u16*   hb     = (u16*)(ws + 88 * MB);   // reuses q/k/v space after attention
  float* outf   = (float*)d_out;

  // all weight + activation casts to bf16, one launch
  CvtArgs ca;
  ca.src[0] = Wq; ca.dst[0] = wb_qkv;
  ca.src[1] = Wk; ca.dst[1] = wb_qkv + 1048576;
  ca.src[2] = Wv; ca.dst[2] = wb_qkv + 2097152;
  ca.src[3] = Wo; ca.dst[3] = wb_o;
  ca.src[4] = W1; ca.dst[4] = wb_1;
  ca.src[5] = W2; ca.dst[5] = wb_2;
  ca.src[6] = x;  ca.dst[6] = xb;
  ca.start[0] = 0;    ca.start[1] = 512;  ca.start[2] = 1024; ca.start[3] = 1536;
  ca.start[4] = 2048; ca.start[5] = 4096; ca.start[6] = 6144; ca.start[7] = 10240;
  cvt_all<<<10240, 256, 0, stream>>>(ca);

  // QKV projection (fused, N=3072); Q pre-scaled; V written transposed
  gemm2<0><<<1536, 512, 0, stream>>>(xb, wb_qkv, 1024, 24, bq, bk, bv,
                                     nullptr, qb, kb, vbt, nullptr);
  // causal flash attention (QBLK=128 per block, 16 q-tiles per bh)
  attn2_kernel<<<dim3(16, 64), 256, 0, stream>>>(qb, kb, vbt, attb);
  // O projection + bias + x residual -> y1 (f32)
  gemm2<1><<<512, 512, 0, stream>>>(attb, wb_o, 1024, 8, bo, nullptr, nullptr,
                                    x, nullptr, nullptr, nullptr, x1f);
  // LN1 in-place; also emit x1 bf16 for FFN1
  ln_kernel<<<8192, 256, 0, stream>>>(x1f, x1f, xb, g1, be1);
  // FFN1 + GELU -> h (bf16)
  gemm2<2><<<2048, 512, 0, stream>>>(xb, wb_1, 1024, 32, b1, nullptr, nullptr,
                                     nullptr, hb, nullptr, nullptr, nullptr);
  // FFN2 + bias + x1 residual -> f32 straight into d_out
  gemm2<3><<<512, 512, 0, stream>>>(hb, wb_2, 4096, 8, b2, nullptr, nullptr,
                                    x1f, nullptr, nullptr, nullptr, outf);
  // LN2 in place on d_out
  ln_kernel<<<8192, 256, 0, stream>>>(outf, outf, nullptr, g2, be2);
}

// Round 10
// 545.180 us; speedup vs baseline: 1.2290x; 1.2290x over previous
//
#include <hip/hip_runtime.h>
#include <hip/hip_bf16.h>

// GPT block: x -> QKV -> causal MHA -> O-proj(+x) -> LN1 -> FFN(GELU) -> (+x1) -> LN2
// B=4 S=2048 D=1024 H=16 hd=64 DFF=4096. All matmuls bf16 MFMA (fp32 accum).
// Workspace layout (bytes):
//   0      wb_qkv  [3072,1024] bf16    6 MB
//   6M     wb_o    [1024,1024] bf16    2 MB
//   8M     wb_1    [4096,1024] bf16    8 MB
//   16M    wb_2    [1024,4096] bf16    8 MB
//   24M    xb      [8192,1024] bf16 (x; later x1 bf16)          16 MB
//   40M    attb    [8192,1024] bf16 (attention out, token-major) 16 MB
//   56M    x1f     [8192,1024] f32 (y1 pre-LN, then x1 post-LN)  32 MB
//   88M    qb/hb   qb [64bh,2048,64] bf16 16MB; hb [8192,4096] bf16 64MB (reuse)
//   104M   kb      [64bh,2048,64] bf16 16 MB
//   120M   vbt     [64bh,64,2048] bf16 (V TRANSPOSED per head) 16 MB
// total 152 MB. FFN2 writes f32 straight to d_out; LN2 runs in place there.

typedef unsigned short u16;
typedef unsigned int u32;
typedef short s16x8 __attribute__((ext_vector_type(8)));   // bf16 MFMA frag
typedef float f32x4 __attribute__((ext_vector_type(4)));
typedef float f32x16 __attribute__((ext_vector_type(16)));
typedef unsigned short u16x8 __attribute__((ext_vector_type(8)));
typedef unsigned short u16x4 __attribute__((ext_vector_type(4)));
typedef unsigned int u32x4 __attribute__((ext_vector_type(4)));

#define MFMA16(a, b, c) __builtin_amdgcn_mfma_f32_16x16x32_bf16(a, b, c, 0, 0, 0)
#define MFMA32(a, b, c) __builtin_amdgcn_mfma_f32_32x32x16_bf16(a, b, c, 0, 0, 0)

#define GLDS16(g, l)                                                     \
  __builtin_amdgcn_global_load_lds(                                     \
      (const __attribute__((address_space(1))) unsigned int*)(g),       \
      (__attribute__((address_space(3))) unsigned int*)(l), 16, 0, 0)

__device__ __forceinline__ u16 f2bf(float f) {
  unsigned u = __builtin_bit_cast(unsigned, f);
  u += 0x7fffu + ((u >> 16) & 1u);   // RNE (inputs are never NaN here)
  return (u16)(u >> 16);
}

// XOR swizzle for 128B-row LDS tiles: permutes 16B chunks within a row by row&7.
__device__ __forceinline__ int swz(int b) { return b ^ (((b >> 7) & 7) << 4); }

// ---------------------------------------------------------------- conversions
struct CvtArgs {
  const float* src[7];
  u16* dst[7];
  int start[8];   // cumulative region starts, in blocks
};

__global__ __launch_bounds__(256) void cvt_all(CvtArgs a) {
  int b = blockIdx.x;
  int r = 0;
#pragma unroll
  for (int i = 1; i < 7; i++) r += (b >= a.start[i]);
  long i = (long)(b - a.start[r]) * 256 + threadIdx.x;
  const float4* s = (const float4*)a.src[r];
  float4 va = s[2 * i], vb = s[2 * i + 1];
  u16x8 o;
  o[0] = f2bf(va.x); o[1] = f2bf(va.y); o[2] = f2bf(va.z); o[3] = f2bf(va.w);
  o[4] = f2bf(vb.x); o[5] = f2bf(vb.y); o[6] = f2bf(vb.z); o[7] = f2bf(vb.w);
  ((u16x8*)a.dst[r])[i] = o;
}

// ---------------------------------------------------------------- GEMM v2 (NT)
// C[m,n] = sum_k A[m,k] * Bt[n,k]; 128x128 tile, BK=64, 8 waves (32x64 each),
// double-buffered LDS (64 KB -> 2 blocks/CU), 2-phase loop: STAGE(t+1) issued
// before compute(t), ONE barrier per K-step. T2 bank-conflict fix: LDS dest
// stays LINEAR; global SOURCE chunk is pre-swizzled (cs = c ^ (row&7)); reads
// apply the same XOR via swz(). 16-way conflict -> 2-way (free, m136).
// EPI: 0=QKV split(+bias, Q*=0.125 -> qb/kb [bh,s,hd]; V -> vbt [bh,hd,s] T)
//      1=Oproj (+bias +x residual -> f32)
//      2=FFN1  (+bias, exact GELU -> bf16, ld 4096)
//      3=FFN2  (+bias +x1 residual -> f32)
template <int EPI>
__global__ __launch_bounds__(512, 4) void gemm2(
    const u16* __restrict__ A, const u16* __restrict__ Bt, int K, int NB,
    const float* __restrict__ c0, const float* __restrict__ c1,
    const float* __restrict__ c2, const float* __restrict__ resid,
    u16* __restrict__ ob0, u16* __restrict__ ob1, u16* __restrict__ ob2,
    float* __restrict__ of) {
  __shared__ u16 As[2][128 * 64];
  __shared__ u16 Bs[2][128 * 64];
  const int tid = threadIdx.x, w = tid >> 6, l = tid & 63;
  const int wrow = w >> 1, wcol = w & 1;          // 4M x 2N wave grid
  const int nwg = gridDim.x, cpx = nwg >> 3, lid = blockIdx.x;
  const int sid = (lid & 7) * cpx + (lid >> 3);   // XCD-contiguous chunks
  const long row0 = (long)(sid / NB) * 128, col0 = (long)(sid % NB) * 128;

  f32x4 acc[2][4];
#pragma unroll
  for (int i = 0; i < 2; i++)
#pragma unroll
    for (int j = 0; j < 4; j++) acc[i][j] = f32x4{0.f, 0.f, 0.f, 0.f};

  // staging: wave w, instr i covers tile rows [i*64 + w*8, +8); lane l ->
  // row +(l>>3), LDS 16B-chunk position (l&7), global chunk cs = (l&7)^(row&7).
  // (w*8 and 64 are 0 mod 8, so row&7 == (l>>3)&7 for both instrs.)
  const int cs = (l & 7) ^ ((l >> 3) & 7);
  const u16* Ag = A + (row0 + w * 8 + (l >> 3)) * (long)K + cs * 8;
  const u16* Bg = Bt + (col0 + w * 8 + (l >> 3)) * (long)K + cs * 8;

#define STAGE2(bf, k0)                                                \
  GLDS16(Ag + (k0),                &As[bf][(w * 8) * 64]);            \
  GLDS16(Ag + (k0) + 64 * (long)K, &As[bf][(64 + w * 8) * 64]);       \
  GLDS16(Bg + (k0),                &Bs[bf][(w * 8) * 64]);            \
  GLDS16(Bg + (k0) + 64 * (long)K, &Bs[bf][(64 + w * 8) * 64]);

  const int nt = K >> 6;
  int cur = 0;
  STAGE2(0, 0)
  __syncthreads();                    // vmcnt(0) drain included
  for (int t = 0; t < nt; ++t) {
    if (t + 1 < nt) { STAGE2(cur ^ 1, (t + 1) << 6) }  // in flight across compute
#pragma unroll
    for (int ks = 0; ks < 2; ks++) {
      s16x8 af[2], bfr[4];
#pragma unroll
      for (int mi = 0; mi < 2; mi++)
        af[mi] = *(const s16x8*)((const char*)&As[cur][0] +
                   swz((wrow * 32 + mi * 16 + (l & 15)) * 128 + ks * 64 + (l >> 4) * 16));
#pragma unroll
      for (int ni = 0; ni < 4; ni++)
        bfr[ni] = *(const s16x8*)((const char*)&Bs[cur][0] +
                   swz((wcol * 64 + ni * 16 + (l & 15)) * 128 + ks * 64 + (l >> 4) * 16));
#pragma unroll
      for (int mi = 0; mi < 2; mi++)
#pragma unroll
        for (int ni = 0; ni < 4; ni++)
          acc[mi][ni] = MFMA16(af[mi], bfr[ni], acc[mi][ni]);
    }
    __syncthreads();                  // STAGE done + all reads of cur done
    cur ^= 1;
  }
#undef STAGE2

#pragma unroll
  for (int mi = 0; mi < 2; mi++)
#pragma unroll
    for (int ni = 0; ni < 4; ni++) {
      long rbase = row0 + wrow * 32 + mi * 16 + ((l >> 4) << 2);
      long col = col0 + wcol * 64 + ni * 16 + (l & 15);
#pragma unroll
      for (int r = 0; r < 4; r++) {
        long row = rbase + r;
        float v = acc[mi][ni][r];
        if constexpr (EPI == 0) {
          int which = (int)(col >> 10);
          int ec = (int)(col & 1023);
          const float* bias = which == 0 ? c0 : (which == 1 ? c1 : c2);
          v += bias[ec];
          if (which == 0) v *= 0.125f;      // 1/sqrt(hd)
          int hh = ec >> 6, dd = ec & 63;
          long bb = row >> 11, sl = row & 2047;
          if (which == 2) {
            ob2[(((bb * 16 + hh) * 64 + dd) << 11) + sl] = f2bf(v);  // V^T
          } else {
            u16* dst = which == 0 ? ob0 : ob1;
            dst[(((bb * 16 + hh) * 2048 + sl) << 6) + dd] = f2bf(v);
          }
        } else if constexpr (EPI == 1) {
          v += c0[col] + resid[row * 1024 + col];
          of[row * 1024 + col] = v;
        } else if constexpr (EPI == 2) {
          v += c0[col];
          v = 0.5f * v * (1.f + erff(v * 0.70710678118654752f));
          ob0[row * 4096 + col] = f2bf(v);
        } else {
          v += c0[col] + resid[row * 1024 + col];
          of[row * 1024 + col] = v;
        }
      }
    }
}

// ---------------------------------------------------------------- attention v2
// Per block: one (b,h), QBLK=128 (4 waves x 32 q-rows). KVBLK=64.
// Swapped QK^T via 32x32x16 MFMA: P[q][s] with q=lane&31 (lane-local row).
// Softmax fully in-register (in-lane reduce + one shfl_xor(32)).
// P -> B-frag repack in-register (pack + shfl_xor(32) + select).
// PV computed as O^T = mfma(V^T, P): per-lane scalar rescale.
// K and V^T staged by global_load_lds with pre-swizzled global source,
// double-buffered, one barrier per tile.
__global__ __launch_bounds__(256, 4) void attn2_kernel(const u16* __restrict__ Qb,
                                                       const u16* __restrict__ Kb,
                                                       const u16* __restrict__ Vbt,
                                                       u16* __restrict__ attb) {
  __shared__ u16 Kt[2][64 * 64];     // [buf][s=64 rows][64 d] swizzled chunks
  __shared__ u16 Vt[2][64 * 64];     // [buf][d=64 rows][64 s] swizzled chunks

  const int tid = threadIdx.x, w = tid >> 6, l = tid & 63;
  const int hi = l >> 5, ln = l & 31;
  const int bh = blockIdx.y;
  const int qt = (int)gridDim.x - 1 - (int)blockIdx.x;  // heavy tiles first
  const int q0w = qt * 128 + w * 32;                    // wave's first q row
  const int q = q0w + ln;                               // this lane's q row
  const long kbase = (long)bh * (2048 * 64);
  const long vbase = (long)bh * (64 * 2048);
  const int tmax = 2 * qt + 1;
  const int cs = (l & 7) ^ ((l >> 3) & 7);              // pre-swizzled source chunk

  // hoist Q row into registers: qf[kk] = Q[q][kk*16 + hi*8 .. +8)
  s16x8 qf[4];
  {
    const char* qp = (const char*)(Qb + kbase) + (long)q * 128 + hi * 16;
#pragma unroll
    for (int kk = 0; kk < 4; kk++) qf[kk] = *(const s16x8*)(qp + kk * 32);
  }

  f32x16 acc0, acc1;
#pragma unroll
  for (int i = 0; i < 16; i++) { acc0[i] = 0.f; acc1[i] = 0.f; }
  float mrow = -1e30f, lsum = 0.f;

  // stage(buf, t): wave w stages K rows [w*16, w*16+16) and V^T rows likewise.
  const u16* kg = Kb + kbase;
  const u16* vg = Vbt + vbase;
#define STAGE(bf, t)                                                            \
  {                                                                             \
    int s0_ = (t) * 64;                                                         \
    GLDS16(kg + (long)(s0_ + w * 16 + (l >> 3)) * 64 + cs * 8,                  \
           (char*)Kt[bf] + w * 2048);                                           \
    GLDS16(kg + (long)(s0_ + w * 16 + 8 + (l >> 3)) * 64 + cs * 8,              \
           (char*)Kt[bf] + w * 2048 + 1024);                                    \
    GLDS16(vg + (long)(w * 16 + (l >> 3)) * 2048 + s0_ + cs * 8,                \
           (char*)Vt[bf] + w * 2048);                                           \
    GLDS16(vg + (long)(w * 16 + 8 + (l >> 3)) * 2048 + s0_ + cs * 8,            \
           (char*)Vt[bf] + w * 2048 + 1024);                                    \
  }

  STAGE(0, 0);

  for (int t = 0; t <= tmax; ++t) {
    __syncthreads();                 // drains this wave's global_load_lds too
    const int cur = t & 1;
    if (t < tmax) STAGE(cur ^ 1, t + 1);
    if (64 * t > q0w + 31) continue; // wave fully masked for this tile (still staged)
    const int s0 = t * 64;

    // ---- QK^T (swapped): p{sb}[r] = P[q][s0 + 32*sb + crow(r,hi)]
    f32x16 p0, p1;
#pragma unroll
    for (int i = 0; i < 16; i++) { p0[i] = 0.f; p1[i] = 0.f; }
#pragma unroll
    for (int kk = 0; kk < 4; kk++) {
      s16x8 kf0 = *(const s16x8*)((char*)Kt[cur] + swz(ln * 128 + kk * 32 + hi * 16));
      s16x8 kf1 = *(const s16x8*)((char*)Kt[cur] + swz((32 + ln) * 128 + kk * 32 + hi * 16));
      p0 = MFMA32(kf0, qf[kk], p0);
      p1 = MFMA32(kf1, qf[kk], p1);
    }

    // ---- causal mask (only near the diagonal)
    if (s0 + 63 > q0w) {
#pragma unroll
      for (int r = 0; r < 16; r++) {
        int so = (r & 3) + 8 * (r >> 2) + 4 * hi;
        if (s0 + so > q) p0[r] = -1e30f;
        if (s0 + 32 + so > q) p1[r] = -1e30f;
      }
    }

    // ---- online softmax (row q is lane-local across the two hi halves)
    float mt = -1e30f;
#pragma unroll
    for (int r = 0; r < 16; r++) { mt = fmaxf(mt, p0[r]); mt = fmaxf(mt, p1[r]); }
    mt = fmaxf(mt, __shfl_xor(mt, 32, 64));
    float mnew = fmaxf(mrow, mt);
    float corr = __expf(mrow - mnew);
    float lp = 0.f;
#pragma unroll
    for (int r = 0; r < 16; r++) {
      p0[r] = __expf(p0[r] - mnew); lp += p0[r];
      p1[r] = __expf(p1[r] - mnew); lp += p1[r];
    }
    lp += __shfl_xor(lp, 32, 64);
    lsum = lsum * corr + lp;
    mrow = mnew;
#pragma unroll
    for (int i = 0; i < 16; i++) { acc0[i] *= corr; acc1[i] *= corr; }

    // ---- repack P into B-fragments pa[kb]: element j = P[q][16*kb + 8*hi + j]
    u32x4 pa[4];
#pragma unroll
    for (int kb = 0; kb < 4; kb++) {
      const int b8 = 8 * (kb & 1);
#pragma unroll
      for (int tt = 0; tt < 2; tt++) {
        float a0, a1, b0, b1;
        if (kb < 2) {
          a0 = p0[b8 + 2 * tt]; a1 = p0[b8 + 2 * tt + 1];
          b0 = p0[b8 + 4 + 2 * tt]; b1 = p0[b8 + 5 + 2 * tt];
        } else {
          a0 = p1[b8 + 2 * tt]; a1 = p1[b8 + 2 * tt + 1];
          b0 = p1[b8 + 4 + 2 * tt]; b1 = p1[b8 + 5 + 2 * tt];
        }
        u32 X = (u32)f2bf(a0) | ((u32)f2bf(a1) << 16);
        u32 Y = (u32)f2bf(b0) | ((u32)f2bf(b1) << 16);
        u32 Xx = __shfl_xor(X, 32, 64), Yx = __shfl_xor(Y, 32, 64);
        pa[kb][tt]     = (hi == 0) ? X : Yx;   // words 0,1 (k bit2 = 0 half)
        pa[kb][tt + 2] = (hi == 0) ? Xx : Y;   // words 2,3
      }
    }

    // ---- PV as O^T: acc[dblk] += mfma(A=V^T frag, B=pa)
#pragma unroll
    for (int kb = 0; kb < 4; kb++) {
      s16x8 pf = __builtin_bit_cast(s16x8, pa[kb]);
      s16x8 vf0 = *(const s16x8*)((char*)Vt[cur] + swz(ln * 128 + kb * 32 + hi * 16));
      s16x8 vf1 = *(const s16x8*)((char*)Vt[cur] + swz((32 + ln) * 128 + kb * 32 + hi * 16));
      acc0 = MFMA32(vf0, pf, acc0);
      acc1 = MFMA32(vf1, pf, acc1);
    }
  }

  // ---- epilogue: attb[b*2048+q][h*64+d], d = 32*dblk + crow(reg,hi)
  const float inv = 1.0f / lsum;
  const long orow = ((long)(bh >> 4) * 2048 + q) * 1024 + (bh & 15) * 64;
#pragma unroll
  for (int dblk = 0; dblk < 2; dblk++) {
#pragma unroll
    for (int rq = 0; rq < 4; rq++) {
      u16x4 o;
#pragma unroll
      for (int e = 0; e < 4; e++) {
        float v = (dblk == 0 ? acc0[rq * 4 + e] : acc1[rq * 4 + e]) * inv;
        o[e] = f2bf(v);
      }
      int d = 32 * dblk + 8 * rq + 4 * hi;
      *(u16x4*)(attb + orow + d) = o;
    }
  }
#undef STAGE
}

// ---------------------------------------------------------------- layernorm
__global__ __launch_bounds__(256) void ln_kernel(const float* __restrict__ in,
                                                 float* __restrict__ outf,
                                                 u16* __restrict__ outb,
                                                 const float* __restrict__ g,
                                                 const float* __restrict__ be) {
  __shared__ float a1[4], a2[4];
  long row = blockIdx.x;
  const float4* p = (const float4*)(in + row * 1024);
  int t = threadIdx.x, w = t >> 6, l = t & 63;
  float4 v = p[t];
  float s = v.x + v.y + v.z + v.w;
#pragma unroll
  for (int off = 1; off < 64; off <<= 1) s += __shfl_xor(s, off, 64);
  if (l == 0) a1[w] = s;
  __syncthreads();
  float mu = (a1[0] + a1[1] + a1[2] + a1[3]) * (1.f / 1024.f);
  float d0 = v.x - mu, d1 = v.y - mu, d2 = v.z - mu, d3 = v.w - mu;
  float q = d0 * d0 + d1 * d1 + d2 * d2 + d3 * d3;
#pragma unroll
  for (int off = 1; off < 64; off <<= 1) q += __shfl_xor(q, off, 64);
  if (l == 0) a2[w] = q;
  __syncthreads();
  float var = (a2[0] + a2[1] + a2[2] + a2[3]) * (1.f / 1024.f);
  float rs = rsqrtf(var + 1e-5f);
  float4 gg = ((const float4*)g)[t], bb = ((const float4*)be)[t];
  float o0 = d0 * rs * gg.x + bb.x, o1 = d1 * rs * gg.y + bb.y;
  float o2 = d2 * rs * gg.z + bb.z, o3 = d3 * rs * gg.w + bb.w;
  if (outf) {
    float4 o; o.x = o0; o.y = o1; o.z = o2; o.w = o3;
    ((float4*)(outf + row * 1024))[t] = o;
  }
  if (outb) {
    u16x4 u; u[0] = f2bf(o0); u[1] = f2bf(o1); u[2] = f2bf(o2); u[3] = f2bf(o3);
    ((u16x4*)outb)[row * 256 + t] = u;
  }
}

// ---------------------------------------------------------------- launch
extern "C" void kernel_launch(void* const* d_in, const int* in_sizes, int n_in,
                              void* d_out, int out_size, void* d_ws, size_t ws_size,
                              hipStream_t stream) {
  const float* x   = (const float*)d_in[0];
  const float* Wq  = (const float*)d_in[1];
  const float* bq  = (const float*)d_in[2];
  const float* Wk  = (const float*)d_in[3];
  const float* bk  = (const float*)d_in[4];
  const float* Wv  = (const float*)d_in[5];
  const float* bv  = (const float*)d_in[6];
  const float* Wo  = (const float*)d_in[7];
  const float* bo  = (const float*)d_in[8];
  const float* W1  = (const float*)d_in[9];
  const float* b1  = (const float*)d_in[10];
  const float* W2  = (const float*)d_in[11];
  const float* b2  = (const float*)d_in[12];
  const float* g1  = (const float*)d_in[13];
  const float* be1 = (const float*)d_in[14];
  const float* g2  = (const float*)d_in[15];
  const float* be2 = (const float*)d_in[16];

  char* ws = (char*)d_ws;
  const size_t MB = 1ull << 20;
  u16*   wb_qkv = (u16*)(ws + 0);
  u16*   wb_o   = (u16*)(ws + 6 * MB);
  u16*   wb_1   = (u16*)(ws + 8 * MB);
  u16*   wb_2   = (u16*)(ws + 16 * MB);
  u16*   xb     = (u16*)(ws + 24 * MB);   // x bf16, later x1 bf16
  u16*   attb   = (u16*)(ws + 40 * MB);
  float* x1f    = (float*)(ws + 56 * MB);
  u16*   qb     = (u16*)(ws + 88 * MB);
  u16*   kb     = (u16*)(ws + 104 * MB);
  u16*   vbt    = (u16*)(ws + 120 * MB);  // V transposed [bh][64][2048]
  u16*   hb     = (u16*)(ws + 88 * MB);   // reuses q/k/v space after attention
  float* outf   = (float*)d_out;

  // all weight + activation casts to bf16, one launch
  CvtArgs ca;
  ca.src[0] = Wq; ca.dst[0] = wb_qkv;
  ca.src[1] = Wk; ca.dst[1] = wb_qkv + 1048576;
  ca.src[2] = Wv; ca.dst[2] = wb_qkv + 2097152;
  ca.src[3] = Wo; ca.dst[3] = wb_o;
  ca.src[4] = W1; ca.dst[4] = wb_1;
  ca.src[5] = W2; ca.dst[5] = wb_2;
  ca.src[6] = x;  ca.dst[6] = xb;
  ca.start[0] = 0;    ca.start[1] = 512;  ca.start[2] = 1024; ca.start[3] = 1536;
  ca.start[4] = 2048; ca.start[5] = 4096; ca.start[6] = 6144; ca.start[7] = 10240;
  cvt_all<<<10240, 256, 0, stream>>>(ca);

  // QKV projection (fused, N=3072); Q pre-scaled; V written transposed
  gemm2<0><<<1536, 512, 0, stream>>>(xb, wb_qkv, 1024, 24, bq, bk, bv,
                                     nullptr, qb, kb, vbt, nullptr);
  // causal flash attention (QBLK=128 per block, 16 q-tiles per bh)
  attn2_kernel<<<dim3(16, 64), 256, 0, stream>>>(qb, kb, vbt, attb);
  // O projection + bias + x residual -> y1 (f32)
  gemm2<1><<<512, 512, 0, stream>>>(attb, wb_o, 1024, 8, bo, nullptr, nullptr,
                                    x, nullptr, nullptr, nullptr, x1f);
  // LN1 in-place; also emit x1 bf16 for FFN1
  ln_kernel<<<8192, 256, 0, stream>>>(x1f, x1f, xb, g1, be1);
  // FFN1 + GELU -> h (bf16)
  gemm2<2><<<2048, 512, 0, stream>>>(xb, wb_1, 1024, 32, b1, nullptr, nullptr,
                                     nullptr, hb, nullptr, nullptr, nullptr);
  // FFN2 + bias + x1 residual -> f32 straight into d_out
  gemm2<3><<<512, 512, 0, stream>>>(hb, wb_2, 4096, 8, b2, nullptr, nullptr,
                                    x1f, nullptr, nullptr, nullptr, outf);
  // LN2 in place on d_out
  ln_kernel<<<8192, 256, 0, stream>>>(outf, outf, nullptr, g2, be2);
}

// Round 11
// 506.526 us; speedup vs baseline: 1.3228x; 1.0763x over previous
//
#include <hip/hip_runtime.h>
#include <hip/hip_bf16.h>

// GPT block: x -> QKV -> causal MHA -> O-proj(+x) -> LN1 -> FFN(GELU) -> (+x1) -> LN2
// B=4 S=2048 D=1024 H=16 hd=64 DFF=4096. All matmuls bf16 MFMA (fp32 accum).
// Workspace layout (bytes):
//   0      wb_qkv  [3072,1024] bf16    6 MB
//   6M     wb_o    [1024,1024] bf16    2 MB
//   8M     wb_1    [4096,1024] bf16    8 MB
//   16M    wb_2    [1024,4096] bf16    8 MB
//   24M    xb      [8192,1024] bf16 (x; later x1 bf16)          16 MB
//   40M    attb    [8192,1024] bf16 (attention out, token-major) 16 MB
//   56M    x1f     [8192,1024] f32 (y1 pre-LN, then x1 post-LN)  32 MB
//   88M    qb/hb   qb [64bh,2048,64] bf16 16MB; hb [8192,4096] bf16 64MB (reuse)
//   104M   kb      [64bh,2048,64] bf16 16 MB
//   120M   vbt     [64bh,64,2048] bf16 (V TRANSPOSED per head) 16 MB
// total 152 MB. FFN2 writes f32 straight to d_out; LN2 runs in place there.

typedef unsigned short u16;
typedef unsigned int u32;
typedef short s16x8 __attribute__((ext_vector_type(8)));   // bf16 MFMA frag
typedef float f32x4 __attribute__((ext_vector_type(4)));
typedef float f32x16 __attribute__((ext_vector_type(16)));
typedef unsigned short u16x8 __attribute__((ext_vector_type(8)));
typedef unsigned short u16x4 __attribute__((ext_vector_type(4)));
typedef unsigned int u32x4 __attribute__((ext_vector_type(4)));

#define MFMA16(a, b, c) __builtin_amdgcn_mfma_f32_16x16x32_bf16(a, b, c, 0, 0, 0)
#define MFMA32(a, b, c) __builtin_amdgcn_mfma_f32_32x32x16_bf16(a, b, c, 0, 0, 0)

#define GLDS16(g, l)                                                     \
  __builtin_amdgcn_global_load_lds(                                     \
      (const __attribute__((address_space(1))) unsigned int*)(g),       \
      (__attribute__((address_space(3))) unsigned int*)(l), 16, 0, 0)

__device__ __forceinline__ u16 f2bf(float f) {
  unsigned u = __builtin_bit_cast(unsigned, f);
  u += 0x7fffu + ((u >> 16) & 1u);   // RNE (inputs are never NaN here)
  return (u16)(u >> 16);
}

// XOR swizzle for 128B-row LDS tiles: permutes 16B chunks within a row by row&7.
__device__ __forceinline__ int swz(int b) { return b ^ (((b >> 7) & 7) << 4); }

// ---------------------------------------------------------------- conversions
struct CvtArgs {
  const float* src[7];
  u16* dst[7];
  int start[8];   // cumulative region starts, in blocks
};

__global__ __launch_bounds__(256) void cvt_all(CvtArgs a) {
  int b = blockIdx.x;
  int r = 0;
#pragma unroll
  for (int i = 1; i < 7; i++) r += (b >= a.start[i]);
  long i = (long)(b - a.start[r]) * 256 + threadIdx.x;
  const float4* s = (const float4*)a.src[r];
  float4 va = s[2 * i], vb = s[2 * i + 1];
  u16x8 o;
  o[0] = f2bf(va.x); o[1] = f2bf(va.y); o[2] = f2bf(va.z); o[3] = f2bf(va.w);
  o[4] = f2bf(vb.x); o[5] = f2bf(vb.y); o[6] = f2bf(vb.z); o[7] = f2bf(vb.w);
  ((u16x8*)a.dst[r])[i] = o;
}

// ---------------------------------------------------------------- GEMM v2 (NT)
// C[m,n] = sum_k A[m,k] * Bt[n,k]; 128x128 tile, BK=64, 8 waves (32x64 each),
// double-buffered LDS (64 KB -> 2 blocks/CU), 2-phase loop: STAGE(t+1) issued
// before compute(t), ONE barrier per K-step. T2 bank-conflict fix: LDS dest
// stays LINEAR; global SOURCE chunk is pre-swizzled (cs = c ^ (row&7)); reads
// apply the same XOR via swz(). 16-way conflict -> 2-way (free, m136).
// EPI: 0=QKV split(+bias, Q*=0.125 -> qb/kb [bh,s,hd]; V -> vbt [bh,hd,s] T)
//      1=Oproj (+bias +x residual -> f32)
//      2=FFN1  (+bias, exact GELU -> bf16, ld 4096)
//      3=FFN2  (+bias +x1 residual -> f32)
template <int EPI>
__global__ __launch_bounds__(512, 4) void gemm2(
    const u16* __restrict__ A, const u16* __restrict__ Bt, int K, int NB,
    const float* __restrict__ c0, const float* __restrict__ c1,
    const float* __restrict__ c2, const float* __restrict__ resid,
    u16* __restrict__ ob0, u16* __restrict__ ob1, u16* __restrict__ ob2,
    float* __restrict__ of) {
  __shared__ u16 As[2][128 * 64];
  __shared__ u16 Bs[2][128 * 64];
  const int tid = threadIdx.x, w = tid >> 6, l = tid & 63;
  const int wrow = w >> 1, wcol = w & 1;          // 4M x 2N wave grid
  const int nwg = gridDim.x, cpx = nwg >> 3, lid = blockIdx.x;
  const int sid = (lid & 7) * cpx + (lid >> 3);   // XCD-contiguous chunks
  const long row0 = (long)(sid / NB) * 128, col0 = (long)(sid % NB) * 128;

  f32x4 acc[2][4];
#pragma unroll
  for (int i = 0; i < 2; i++)
#pragma unroll
    for (int j = 0; j < 4; j++) acc[i][j] = f32x4{0.f, 0.f, 0.f, 0.f};

  // staging: wave w, instr i covers tile rows [i*64 + w*8, +8); lane l ->
  // row +(l>>3), LDS 16B-chunk position (l&7), global chunk cs = (l&7)^(row&7).
  // (w*8 and 64 are 0 mod 8, so row&7 == (l>>3)&7 for both instrs.)
  const int cs = (l & 7) ^ ((l >> 3) & 7);
  const u16* Ag = A + (row0 + w * 8 + (l >> 3)) * (long)K + cs * 8;
  const u16* Bg = Bt + (col0 + w * 8 + (l >> 3)) * (long)K + cs * 8;

#define STAGE2(bf, k0)                                                \
  GLDS16(Ag + (k0),                &As[bf][(w * 8) * 64]);            \
  GLDS16(Ag + (k0) + 64 * (long)K, &As[bf][(64 + w * 8) * 64]);       \
  GLDS16(Bg + (k0),                &Bs[bf][(w * 8) * 64]);            \
  GLDS16(Bg + (k0) + 64 * (long)K, &Bs[bf][(64 + w * 8) * 64]);

  const int nt = K >> 6;
  int cur = 0;
  STAGE2(0, 0)
  __syncthreads();                    // vmcnt(0) drain included
  for (int t = 0; t < nt; ++t) {
    if (t + 1 < nt) { STAGE2(cur ^ 1, (t + 1) << 6) }  // in flight across compute
#pragma unroll
    for (int ks = 0; ks < 2; ks++) {
      s16x8 af[2], bfr[4];
#pragma unroll
      for (int mi = 0; mi < 2; mi++)
        af[mi] = *(const s16x8*)((const char*)&As[cur][0] +
                   swz((wrow * 32 + mi * 16 + (l & 15)) * 128 + ks * 64 + (l >> 4) * 16));
#pragma unroll
      for (int ni = 0; ni < 4; ni++)
        bfr[ni] = *(const s16x8*)((const char*)&Bs[cur][0] +
                   swz((wcol * 64 + ni * 16 + (l & 15)) * 128 + ks * 64 + (l >> 4) * 16));
#pragma unroll
      for (int mi = 0; mi < 2; mi++)
#pragma unroll
        for (int ni = 0; ni < 4; ni++)
          acc[mi][ni] = MFMA16(af[mi], bfr[ni], acc[mi][ni]);
    }
    __syncthreads();                  // STAGE done + all reads of cur done
    cur ^= 1;
  }
#undef STAGE2

#pragma unroll
  for (int mi = 0; mi < 2; mi++)
#pragma unroll
    for (int ni = 0; ni < 4; ni++) {
      long rbase = row0 + wrow * 32 + mi * 16 + ((l >> 4) << 2);
      long col = col0 + wcol * 64 + ni * 16 + (l & 15);
#pragma unroll
      for (int r = 0; r < 4; r++) {
        long row = rbase + r;
        float v = acc[mi][ni][r];
        if constexpr (EPI == 0) {
          int which = (int)(col >> 10);
          int ec = (int)(col & 1023);
          const float* bias = which == 0 ? c0 : (which == 1 ? c1 : c2);
          v += bias[ec];
          if (which == 0) v *= 0.125f;      // 1/sqrt(hd)
          int hh = ec >> 6, dd = ec & 63;
          long bb = row >> 11, sl = row & 2047;
          if (which == 2) {
            ob2[(((bb * 16 + hh) * 64 + dd) << 11) + sl] = f2bf(v);  // V^T
          } else {
            u16* dst = which == 0 ? ob0 : ob1;
            dst[(((bb * 16 + hh) * 2048 + sl) << 6) + dd] = f2bf(v);
          }
        } else if constexpr (EPI == 1) {
          v += c0[col] + resid[row * 1024 + col];
          of[row * 1024 + col] = v;
        } else if constexpr (EPI == 2) {
          v += c0[col];
          v = 0.5f * v * (1.f + erff(v * 0.70710678118654752f));
          ob0[row * 4096 + col] = f2bf(v);
        } else {
          v += c0[col] + resid[row * 1024 + col];
          of[row * 1024 + col] = v;
        }
      }
    }
}

// ---------------------------------------------------------------- attention v3
// 1D grid of 1024 blocks; per block: one (b,h) + one 128-row Q tile (4 waves x
// 32 q-rows), KVBLK=64. BALANCED qt mapping: bh = j&63, g = j>>6,
// qt = 4*(g>>2) + (((g>>2)+(g&3))&3)  — bijective over qt per bh, and any CU
// holding blocks {j, j+256, j+512, j+768} gets qt summing to 30 (constant), so
// per-CU causal work is uniform (fixes measured 18.6% occupancy / CU-imbalance).
// Same-bh blocks co-reside per CU -> K/V L2 reuse.
// Swapped QK^T (32x32x16): P row lane-local; in-register softmax; in-register
// P->B-frag repack; PV as O^T = mfma(V^T, P). T5 setprio around MFMA clusters.
__global__ __launch_bounds__(256, 4) void attn2_kernel(const u16* __restrict__ Qb,
                                                       const u16* __restrict__ Kb,
                                                       const u16* __restrict__ Vbt,
                                                       u16* __restrict__ attb) {
  __shared__ u16 Kt[2][64 * 64];     // [buf][s=64 rows][64 d] swizzled chunks
  __shared__ u16 Vt[2][64 * 64];     // [buf][d=64 rows][64 s] swizzled chunks

  const int tid = threadIdx.x, w = tid >> 6, l = tid & 63;
  const int hi = l >> 5, ln = l & 31;
  const int j = blockIdx.x;                             // 0..1023
  const int bh = j & 63;
  const int g = j >> 6;                                 // 0..15
  const int qt = 4 * (g >> 2) + (((g >> 2) + (g & 3)) & 3);  // balanced, bijective
  const int q0w = qt * 128 + w * 32;                    // wave's first q row
  const int q = q0w + ln;                               // this lane's q row
  const long kbase = (long)bh * (2048 * 64);
  const long vbase = (long)bh * (64 * 2048);
  const int tmax = 2 * qt + 1;
  const int cs = (l & 7) ^ ((l >> 3) & 7);              // pre-swizzled source chunk

  // hoist Q row into registers: qf[kk] = Q[q][kk*16 + hi*8 .. +8)
  s16x8 qf[4];
  {
    const char* qp = (const char*)(Qb + kbase) + (long)q * 128 + hi * 16;
#pragma unroll
    for (int kk = 0; kk < 4; kk++) qf[kk] = *(const s16x8*)(qp + kk * 32);
  }

  f32x16 acc0, acc1;
#pragma unroll
  for (int i = 0; i < 16; i++) { acc0[i] = 0.f; acc1[i] = 0.f; }
  float mrow = -1e30f, lsum = 0.f;

  // stage(buf, t): wave w stages K rows [w*16, w*16+16) and V^T rows likewise.
  const u16* kg = Kb + kbase;
  const u16* vg = Vbt + vbase;
#define STAGE(bf, t)                                                            \
  {                                                                             \
    int s0_ = (t) * 64;                                                         \
    GLDS16(kg + (long)(s0_ + w * 16 + (l >> 3)) * 64 + cs * 8,                  \
           (char*)Kt[bf] + w * 2048);                                           \
    GLDS16(kg + (long)(s0_ + w * 16 + 8 + (l >> 3)) * 64 + cs * 8,              \
           (char*)Kt[bf] + w * 2048 + 1024);                                    \
    GLDS16(vg + (long)(w * 16 + (l >> 3)) * 2048 + s0_ + cs * 8,                \
           (char*)Vt[bf] + w * 2048);                                           \
    GLDS16(vg + (long)(w * 16 + 8 + (l >> 3)) * 2048 + s0_ + cs * 8,            \
           (char*)Vt[bf] + w * 2048 + 1024);                                    \
  }

  STAGE(0, 0);

  for (int t = 0; t <= tmax; ++t) {
    __syncthreads();                 // drains this wave's global_load_lds too
    const int cur = t & 1;
    if (t < tmax) STAGE(cur ^ 1, t + 1);
    if (64 * t > q0w + 31) continue; // wave fully masked for this tile (still staged)
    const int s0 = t * 64;

    // ---- QK^T (swapped): p{sb}[r] = P[q][s0 + 32*sb + crow(r,hi)]
    f32x16 p0, p1;
#pragma unroll
    for (int i = 0; i < 16; i++) { p0[i] = 0.f; p1[i] = 0.f; }
    __builtin_amdgcn_s_setprio(1);
#pragma unroll
    for (int kk = 0; kk < 4; kk++) {
      s16x8 kf0 = *(const s16x8*)((char*)Kt[cur] + swz(ln * 128 + kk * 32 + hi * 16));
      s16x8 kf1 = *(const s16x8*)((char*)Kt[cur] + swz((32 + ln) * 128 + kk * 32 + hi * 16));
      p0 = MFMA32(kf0, qf[kk], p0);
      p1 = MFMA32(kf1, qf[kk], p1);
    }
    __builtin_amdgcn_s_setprio(0);

    // ---- causal mask (only near the diagonal)
    if (s0 + 63 > q0w) {
#pragma unroll
      for (int r = 0; r < 16; r++) {
        int so = (r & 3) + 8 * (r >> 2) + 4 * hi;
        if (s0 + so > q) p0[r] = -1e30f;
        if (s0 + 32 + so > q) p1[r] = -1e30f;
      }
    }

    // ---- online softmax (row q is lane-local across the two hi halves)
    float mt = -1e30f;
#pragma unroll
    for (int r = 0; r < 16; r++) { mt = fmaxf(mt, p0[r]); mt = fmaxf(mt, p1[r]); }
    mt = fmaxf(mt, __shfl_xor(mt, 32, 64));
    float mnew = fmaxf(mrow, mt);
    float corr = __expf(mrow - mnew);
    float lp = 0.f;
#pragma unroll
    for (int r = 0; r < 16; r++) {
      p0[r] = __expf(p0[r] - mnew); lp += p0[r];
      p1[r] = __expf(p1[r] - mnew); lp += p1[r];
    }
    lp += __shfl_xor(lp, 32, 64);
    lsum = lsum * corr + lp;
    mrow = mnew;
#pragma unroll
    for (int i = 0; i < 16; i++) { acc0[i] *= corr; acc1[i] *= corr; }

    // ---- repack P into B-fragments pa[kb]: element j = P[q][16*kb + 8*hi + j]
    u32x4 pa[4];
#pragma unroll
    for (int kb = 0; kb < 4; kb++) {
      const int b8 = 8 * (kb & 1);
#pragma unroll
      for (int tt = 0; tt < 2; tt++) {
        float a0, a1, b0, b1;
        if (kb < 2) {
          a0 = p0[b8 + 2 * tt]; a1 = p0[b8 + 2 * tt + 1];
          b0 = p0[b8 + 4 + 2 * tt]; b1 = p0[b8 + 5 + 2 * tt];
        } else {
          a0 = p1[b8 + 2 * tt]; a1 = p1[b8 + 2 * tt + 1];
          b0 = p1[b8 + 4 + 2 * tt]; b1 = p1[b8 + 5 + 2 * tt];
        }
        u32 X = (u32)f2bf(a0) | ((u32)f2bf(a1) << 16);
        u32 Y = (u32)f2bf(b0) | ((u32)f2bf(b1) << 16);
        u32 Xx = __shfl_xor(X, 32, 64), Yx = __shfl_xor(Y, 32, 64);
        pa[kb][tt]     = (hi == 0) ? X : Yx;   // words 0,1 (k bit2 = 0 half)
        pa[kb][tt + 2] = (hi == 0) ? Xx : Y;   // words 2,3
      }
    }

    // ---- PV as O^T: acc[dblk] += mfma(A=V^T frag, B=pa)
    __builtin_amdgcn_s_setprio(1);
#pragma unroll
    for (int kb = 0; kb < 4; kb++) {
      s16x8 pf = __builtin_bit_cast(s16x8, pa[kb]);
      s16x8 vf0 = *(const s16x8*)((char*)Vt[cur] + swz(ln * 128 + kb * 32 + hi * 16));
      s16x8 vf1 = *(const s16x8*)((char*)Vt[cur] + swz((32 + ln) * 128 + kb * 32 + hi * 16));
      acc0 = MFMA32(vf0, pf, acc0);
      acc1 = MFMA32(vf1, pf, acc1);
    }
    __builtin_amdgcn_s_setprio(0);
  }

  // ---- epilogue: attb[b*2048+q][h*64+d], d = 32*dblk + crow(reg,hi)
  const float inv = 1.0f / lsum;
  const long orow = ((long)(bh >> 4) * 2048 + q) * 1024 + (bh & 15) * 64;
#pragma unroll
  for (int dblk = 0; dblk < 2; dblk++) {
#pragma unroll
    for (int rq = 0; rq < 4; rq++) {
      u16x4 o;
#pragma unroll
      for (int e = 0; e < 4; e++) {
        float v = (dblk == 0 ? acc0[rq * 4 + e] : acc1[rq * 4 + e]) * inv;
        o[e] = f2bf(v);
      }
      int d = 32 * dblk + 8 * rq + 4 * hi;
      *(u16x4*)(attb + orow + d) = o;
    }
  }
#undef STAGE
}

// ---------------------------------------------------------------- layernorm
__global__ __launch_bounds__(256) void ln_kernel(const float* __restrict__ in,
                                                 float* __restrict__ outf,
                                                 u16* __restrict__ outb,
                                                 const float* __restrict__ g,
                                                 const float* __restrict__ be) {
  __shared__ float a1[4], a2[4];
  long row = blockIdx.x;
  const float4* p = (const float4*)(in + row * 1024);
  int t = threadIdx.x, w = t >> 6, l = t & 63;
  float4 v = p[t];
  float s = v.x + v.y + v.z + v.w;
#pragma unroll
  for (int off = 1; off < 64; off <<= 1) s += __shfl_xor(s, off, 64);
  if (l == 0) a1[w] = s;
  __syncthreads();
  float mu = (a1[0] + a1[1] + a1[2] + a1[3]) * (1.f / 1024.f);
  float d0 = v.x - mu, d1 = v.y - mu, d2 = v.z - mu, d3 = v.w - mu;
  float q = d0 * d0 + d1 * d1 + d2 * d2 + d3 * d3;
#pragma unroll
  for (int off = 1; off < 64; off <<= 1) q += __shfl_xor(q, off, 64);
  if (l == 0) a2[w] = q;
  __syncthreads();
  float var = (a2[0] + a2[1] + a2[2] + a2[3]) * (1.f / 1024.f);
  float rs = rsqrtf(var + 1e-5f);
  float4 gg = ((const float4*)g)[t], bb = ((const float4*)be)[t];
  float o0 = d0 * rs * gg.x + bb.x, o1 = d1 * rs * gg.y + bb.y;
  float o2 = d2 * rs * gg.z + bb.z, o3 = d3 * rs * gg.w + bb.w;
  if (outf) {
    float4 o; o.x = o0; o.y = o1; o.z = o2; o.w = o3;
    ((float4*)(outf + row * 1024))[t] = o;
  }
  if (outb) {
    u16x4 u; u[0] = f2bf(o0); u[1] = f2bf(o1); u[2] = f2bf(o2); u[3] = f2bf(o3);
    ((u16x4*)outb)[row * 256 + t] = u;
  }
}

// ---------------------------------------------------------------- launch
extern "C" void kernel_launch(void* const* d_in, const int* in_sizes, int n_in,
                              void* d_out, int out_size, void* d_ws, size_t ws_size,
                              hipStream_t stream) {
  const float* x   = (const float*)d_in[0];
  const float* Wq  = (const float*)d_in[1];
  const float* bq  = (const float*)d_in[2];
  const float* Wk  = (const float*)d_in[3];
  const float* bk  = (const float*)d_in[4];
  const float* Wv  = (const float*)d_in[5];
  const float* bv  = (const float*)d_in[6];
  const float* Wo  = (const float*)d_in[7];
  const float* bo  = (const float*)d_in[8];
  const float* W1  = (const float*)d_in[9];
  const float* b1  = (const float*)d_in[10];
  const float* W2  = (const float*)d_in[11];
  const float* b2  = (const float*)d_in[12];
  const float* g1  = (const float*)d_in[13];
  const float* be1 = (const float*)d_in[14];
  const float* g2  = (const float*)d_in[15];
  const float* be2 = (const float*)d_in[16];

  char* ws = (char*)d_ws;
  const size_t MB = 1ull << 20;
  u16*   wb_qkv = (u16*)(ws + 0);
  u16*   wb_o   = (u16*)(ws + 6 * MB);
  u16*   wb_1   = (u16*)(ws + 8 * MB);
  u16*   wb_2   = (u16*)(ws + 16 * MB);
  u16*   xb     = (u16*)(ws + 24 * MB);   // x bf16, later x1 bf16
  u16*   attb   = (u16*)(ws + 40 * MB);
  float* x1f    = (float*)(ws + 56 * MB);
  u16*   qb     = (u16*)(ws + 88 * MB);
  u16*   kb     = (u16*)(ws + 104 * MB);
  u16*   vbt    = (u16*)(ws + 120 * MB);  // V transposed [bh][64][2048]
  u16*   hb     = (u16*)(ws + 88 * MB);   // reuses q/k/v space after attention
  float* outf   = (float*)d_out;

  // all weight + activation casts to bf16, one launch
  CvtArgs ca;
  ca.src[0] = Wq; ca.dst[0] = wb_qkv;
  ca.src[1] = Wk; ca.dst[1] = wb_qkv + 1048576;
  ca.src[2] = Wv; ca.dst[2] = wb_qkv + 2097152;
  ca.src[3] = Wo; ca.dst[3] = wb_o;
  ca.src[4] = W1; ca.dst[4] = wb_1;
  ca.src[5] = W2; ca.dst[5] = wb_2;
  ca.src[6] = x;  ca.dst[6] = xb;
  ca.start[0] = 0;    ca.start[1] = 512;  ca.start[2] = 1024; ca.start[3] = 1536;
  ca.start[4] = 2048; ca.start[5] = 4096; ca.start[6] = 6144; ca.start[7] = 10240;
  cvt_all<<<10240, 256, 0, stream>>>(ca);

  // QKV projection (fused, N=3072); Q pre-scaled; V written transposed
  gemm2<0><<<1536, 512, 0, stream>>>(xb, wb_qkv, 1024, 24, bq, bk, bv,
                                     nullptr, qb, kb, vbt, nullptr);
  // causal flash attention (balanced 1D grid: 64 bh x 16 q-tiles)
  attn2_kernel<<<1024, 256, 0, stream>>>(qb, kb, vbt, attb);
  // O projection + bias + x residual -> y1 (f32)
  gemm2<1><<<512, 512, 0, stream>>>(attb, wb_o, 1024, 8, bo, nullptr, nullptr,
                                    x, nullptr, nullptr, nullptr, x1f);
  // LN1 in-place; also emit x1 bf16 for FFN1
  ln_kernel<<<8192, 256, 0, stream>>>(x1f, x1f, xb, g1, be1);
  // FFN1 + GELU -> h (bf16)
  gemm2<2><<<2048, 512, 0, stream>>>(xb, wb_1, 1024, 32, b1, nullptr, nullptr,
                                     nullptr, hb, nullptr, nullptr, nullptr);
  // FFN2 + bias + x1 residual -> f32 straight into d_out
  gemm2<3><<<512, 512, 0, stream>>>(hb, wb_2, 4096, 8, b2, nullptr, nullptr,
                                    x1f, nullptr, nullptr, nullptr, outf);
  // LN2 in place on d_out
  ln_kernel<<<8192, 256, 0, stream>>>(outf, outf, nullptr, g2, be2);
}